// Round 11
// baseline (339.698 us; speedup 1.0000x reference)
//
#include <hip/hip_runtime.h>
#include <math.h>

#define FIELD 2097152   // 32*512*128
#define NSEQ  4096      // 32*128 sequences

typedef float f2 __attribute__((ext_vector_type(2)));   // (re, im) -> VGPR pair

__device__ __forceinline__ f2 cmuli(f2 a)  { return (f2){-a.y, a.x}; }  //  i*a
__device__ __forceinline__ f2 cmulni(f2 a) { return (f2){a.y, -a.x}; }  // -i*a
__device__ __forceinline__ f2 conjf2(f2 a) { return (f2){a.x, -a.y}; }
__device__ __forceinline__ f2 cmul(f2 a, float c, float s) {   // a*(c+is)
  return c * a + s * cmuli(a);
}
__device__ __forceinline__ f2 cmulc(f2 a, float c, float s) {  // a*(c-is)
  return c * a - s * cmuli(a);
}
__device__ __forceinline__ f2 shflx2(f2 v, int h) {
  return (f2){__shfl_xor(v.x, h, 64), __shfl_xor(v.y, h, 64)};
}
__device__ __forceinline__ f2 shfl2(f2 v, int l) {
  return (f2){__shfl(v.x, l, 64), __shfl(v.y, l, 64)};
}

__device__ __forceinline__ void fft4_fwd(f2* v) {
  f2 t0 = v[0] + v[2], t1 = v[0] - v[2];
  f2 t2 = v[1] + v[3], t3 = v[1] - v[3];
  v[0] = t0 + t2; v[2] = t0 - t2;
  v[1] = t1 + cmulni(t3);
  v[3] = t1 + cmuli(t3);
}
__device__ __forceinline__ void fft4_inv(f2* v) {
  f2 t0 = v[0] + v[2], t1 = v[0] - v[2];
  f2 t2 = v[1] + v[3], t3 = v[1] - v[3];
  v[0] = t0 + t2; v[2] = t0 - t2;
  v[1] = t1 + cmuli(t3);
  v[3] = t1 + cmulni(t3);
}

// Dual-sequence 256-pt FFT, j-innermost interleave for ILP (in-order issue:
// two independent chains convert dependency stalls into issue slots).
__device__ __forceinline__ void fft256_fwd2(f2 v[2][4],
                                            const float* twFr, const float* twFi,
                                            const float* Wr, const float* Wi,
                                            int lane) {
#pragma unroll
  for (int j = 0; j < 2; ++j) fft4_fwd(v[j]);
#pragma unroll
  for (int b = 1; b < 4; ++b)
#pragma unroll
    for (int j = 0; j < 2; ++j) v[j][b] = cmul(v[j][b], twFr[b-1], twFi[b-1]);
#pragma unroll
  for (int s = 0; s < 6; ++s) {
    const int h = 32 >> s;
    const bool hi = (lane & h) != 0;
    const float sg = hi ? -1.0f : 1.0f;
#pragma unroll
    for (int b = 0; b < 4; ++b)
#pragma unroll
      for (int j = 0; j < 2; ++j) {
        f2 p = shflx2(v[j][b], h);
        f2 t = sg * v[j][b] + p;
        f2 m = cmul(t, Wr[s], Wi[s]);
        v[j][b] = hi ? m : t;
      }
  }
}

__device__ __forceinline__ void ifft256_2(f2 v[2][4],
                                          const float* twFr, const float* twFi,
                                          const float* Wr, const float* Wi,
                                          int lane) {
#pragma unroll
  for (int s = 5; s >= 0; --s) {
    const int h = 32 >> s;
    const bool hi = (lane & h) != 0;
    const float sg = hi ? -1.0f : 1.0f;
#pragma unroll
    for (int b = 0; b < 4; ++b)
#pragma unroll
      for (int j = 0; j < 2; ++j) {
        f2 p = shflx2(v[j][b], h);
        f2 q = hi ? v[j][b] : p;
        f2 r = hi ? p : v[j][b];
        f2 t = cmulc(q, Wr[s], Wi[s]);
        v[j][b] = sg * t + r;
      }
  }
#pragma unroll
  for (int b = 1; b < 4; ++b)
#pragma unroll
    for (int j = 0; j < 2; ++j) v[j][b] = cmulc(v[j][b], twFr[b-1], twFi[b-1]);
#pragma unroll
  for (int j = 0; j < 2; ++j) fft4_inv(v[j]);
}

__device__ __forceinline__ void half_to_z2(f2 S[2][4], const float* S256,
                                           const float* twHr, const float* twHi,
                                           int lane, int pl0, int plx) {
  f2 P[2][4];
#pragma unroll
  for (int j = 0; j < 2; ++j) {
    P[j][0] = shfl2(S[j][0], pl0);
#pragma unroll
    for (int b = 1; b < 4; ++b) P[j][b] = shfl2(S[j][4 - b], plx);
    P[j][0] = (lane == 0) ? (f2){S256[j], 0.0f} : P[j][0];
  }
#pragma unroll
  for (int b = 0; b < 4; ++b)
#pragma unroll
    for (int j = 0; j < 2; ++j) {
      f2 cP = conjf2(P[j][b]);
      f2 A = 0.5f * (S[j][b] + cP);
      f2 B = 0.5f * (S[j][b] - cP);
      f2 Bt = cmul(B, twHr[b], twHi[b]);
      S[j][b] = A + cmuli(Bt);
    }
}

__device__ __forceinline__ void mode_update4_2(const f2 X[2][4], const f2 V[2][4],
                                               f2 U[2][4],
                                               const float lam1[2][4],
                                               const float lam2[2][4],
                                               const float* om, float f0) {
#pragma unroll
  for (int b = 0; b < 4; ++b) {
    float f = f0 + (float)b * (1.0f / 512.0f);
#pragma unroll
    for (int j = 0; j < 2; ++j) {
      float dfp = f - om[j];
      float dfm = f + om[j];
      float gp = __builtin_amdgcn_rcpf(fmaf(1600.0f * dfp, dfp, 1.0f));
      float gm = __builtin_amdgcn_rcpf(fmaf(1600.0f * dfm, dfm, 1.0f));
      float gs = 0.5f * (gp + gm);
      f2 D = X[j][b] - V[j][b];
      float lt = 0.25f * fmaf(lam1[j][b], gp, lam2[j][b] * gm);
      U[j][b] = gs * D + (f2){lt, 0.0f};
    }
  }
}

// TWO sequences per wave (doubled ILP — round 10 showed VALUBusy capped at
// ~64% by per-wave dependency stalls with wave count at its hard cap of
// 4096 = 16/CU). 512 blocks x 4 waves x 2 seqs; 8 waves/CU (2/SIMD).
// waves_per_eu(2,2): empirical allocator law budget = 256/min_waves -> 128,
// >= demand (~125; lambda kept in LDS RMW to stay under). XCD swizzle keeps
// consecutive-d blocks on one XCD.
__global__ __attribute__((amdgpu_flat_work_group_size(256, 256),
                          amdgpu_waves_per_eu(2, 2)))
void vmd_kernel(const float* __restrict__ x, float* __restrict__ out) {
  __shared__ float stage[8 * 512];    // [seq][n]; x resident during loop, reused for out
  __shared__ float ldsLam[8 * 512];   // psi-permuted lambda per sequence

  const int tid = threadIdx.x;
  const int wv = tid >> 6;
  const int lane = tid & 63;
  const int w = (blockIdx.x >> 3) + ((blockIdx.x & 7) << 6);   // 0..511, XCD swizzle
  const int bb = w >> 4;
  const int d0 = (8 * w) & 127;
  const int base4 = bb * 16384 + (d0 >> 2);   // float4 index of (bb,0,d0)
  const int g0 = 8 * w + 2 * wv;              // first of this wave's 2 seq ids

  float* lamL[2] = {ldsLam + (2 * wv) * 512, ldsLam + (2 * wv + 1) * 512};
  f2* stg[2] = {(f2*)stage + (2 * wv) * 256, (f2*)stage + (2 * wv + 1) * 256};

  const int rev = (int)(__brev((unsigned)lane) >> 26);   // rev6(lane)
  const float f0 = (float)rev * (1.0f / 128.0f);
  const int plx = lane ^ 63;
  const int pl0 = (int)(__brev((unsigned)((64 - rev) & 63)) >> 26);

  float Wr[6], Wi[6];
#pragma unroll
  for (int s = 0; s < 6; ++s) {
    const int h = 32 >> s;
    float th = (float)(lane & (h - 1)) * (3.14159265358979323846f / (float)h);
    float sn, cs; sincosf(th, &sn, &cs);
    Wr[s] = cs; Wi[s] = -sn;
  }
  float twFr[3], twFi[3];
#pragma unroll
  for (int b = 1; b < 4; ++b) {
    float th = (float)(lane * b) * 0.02454369260617026f;   // 2pi/256
    float sn, cs; sincosf(th, &sn, &cs);
    twFr[b-1] = cs; twFi[b-1] = -sn;
  }
  float twHr[4], twHi[4];
#pragma unroll
  for (int b = 0; b < 4; ++b) {
    float th = (float)(4 * rev + b) * 0.01227184630308513f; // 2pi/512
    float sn, cs; sincosf(th, &sn, &cs);
    twHr[b] = cs; twHi[b] = sn;
  }

  // ---- load x: float4 (n, d0+4c..d0+4c+3) -> stage[4c+s][n]; zero lambda ----
  {
    const float4* x4 = (const float4*)x;
#pragma unroll
    for (int r = 0; r < 2; ++r) {
      const int n = tid + r * 256;
#pragma unroll
      for (int c = 0; c < 2; ++c) {
        float4 va = x4[base4 + n * 32 + c];
        stage[(4 * c + 0) * 512 + n] = va.x;
        stage[(4 * c + 1) * 512 + n] = va.y;
        stage[(4 * c + 2) * 512 + n] = va.z;
        stage[(4 * c + 3) * 512 + n] = va.w;
      }
    }
#pragma unroll
    for (int j = 0; j < 16; ++j) ldsLam[tid * 16 + j] = 0.0f;
  }
  __syncthreads();

  // ---- initial FFT (both seqs) straight from LDS ----
  f2 z[2][4];
#pragma unroll
  for (int j = 0; j < 2; ++j)
#pragma unroll
    for (int a = 0; a < 4; ++a) z[j][a] = stg[j][64 * a + lane];
  fft256_fwd2(z, twFr, twFi, Wr, Wi, lane);
  f2 X[2][4];
  float X256[2];
  {
    f2 P[2][4];
#pragma unroll
    for (int j = 0; j < 2; ++j) {
      P[j][0] = shfl2(z[j][0], pl0);
#pragma unroll
      for (int b = 1; b < 4; ++b) P[j][b] = shfl2(z[j][4 - b], plx);
      X256[j] = __shfl(z[j][0].x - z[j][0].y, 0, 64);
    }
#pragma unroll
    for (int b = 0; b < 4; ++b)
#pragma unroll
      for (int j = 0; j < 2; ++j) {
        f2 cP = conjf2(P[j][b]);
        f2 E = 0.5f * (z[j][b] + cP);
        f2 O = 0.5f * cmulni(z[j][b] - cP);
        X[j][b] = E + cmulc(O, twHr[b], twHi[b]);
      }
  }

  f2 U0[2][4], U1[2][4];
#pragma unroll
  for (int j = 0; j < 2; ++j)
#pragma unroll
    for (int b = 0; b < 4; ++b) {
      U0[j][b] = (f2){0.0f, 0.0f}; U1[j][b] = (f2){0.0f, 0.0f};
    }
  float U0_256[2] = {0.0f, 0.0f}, U1_256[2] = {0.0f, 0.0f};
  float om0[2] = {0.0f, 0.0f}, om1[2] = {0.0f, 0.0f};

  const int psiE = 256 * (lane & 1) + (lane >> 1);   // lambda write base

#pragma unroll 1
  for (int it = 0; it < 50; ++it) {
    float lam1[2][4], lam2[2][4], lam0[2];
#pragma unroll
    for (int j = 0; j < 2; ++j) {
#pragma unroll
      for (int b = 0; b < 4; ++b) lam1[j][b] = lamL[j][128 * b + 64 + rev];
      lam2[j][0] = lamL[j][64 - rev];
#pragma unroll
      for (int b = 1; b < 4; ++b) lam2[j][b] = lamL[j][128 * (4 - b) + 63 - rev];
      lam0[j] = lamL[j][0];
    }

    mode_update4_2(X, U1, U0, lam1, lam2, om0, f0);
#pragma unroll
    for (int j = 0; j < 2; ++j) {
      float dm = 0.5f + om0[j];
      float gg = __builtin_amdgcn_rcpf(fmaf(1600.0f * dm, dm, 1.0f));
      U0_256[j] = (X256[j] - U1_256[j] + 0.5f * lam0[j]) * gg;
    }
    mode_update4_2(X, U0, U1, lam1, lam2, om1, f0);
#pragma unroll
    for (int j = 0; j < 2; ++j) {
      float dm = 0.5f + om1[j];
      float gg = __builtin_amdgcn_rcpf(fmaf(1600.0f * dm, dm, 1.0f));
      U1_256[j] = (X256[j] - U0_256[j] + 0.5f * lam0[j]) * gg;
    }

    // omega: packed (num,den) per mode per seq — 4 independent reduce chains
    f2 s0[2] = {(f2){0.0f, 0.0f}, (f2){0.0f, 0.0f}};
    f2 s1[2] = {(f2){0.0f, 0.0f}, (f2){0.0f, 0.0f}};
#pragma unroll
    for (int b = 0; b < 4; ++b) {
      float f = f0 + (float)b * (1.0f / 512.0f);
#pragma unroll
      for (int j = 0; j < 2; ++j) {
        float p0 = fmaf(U0[j][b].x, U0[j][b].x, U0[j][b].y * U0[j][b].y);
        float p1 = fmaf(U1[j][b].x, U1[j][b].x, U1[j][b].y * U1[j][b].y);
        s0[j] = s0[j] + (f2){f * p0, p0};
        s1[j] = s1[j] + (f2){f * p1, p1};
      }
    }
#pragma unroll
    for (int off = 32; off >= 1; off >>= 1)
#pragma unroll
      for (int j = 0; j < 2; ++j) {
        s0[j] = s0[j] + shflx2(s0[j], off);
        s1[j] = s1[j] + shflx2(s1[j], off);
      }
#pragma unroll
    for (int j = 0; j < 2; ++j) {
      om0[j] = s0[j].x / (s0[j].y + 1e-7f);
      om1[j] = s1[j].x / (s1[j].y + 1e-7f);
    }

    if (it < 49) {   // last iteration's lambda is never consumed
      float S256[2];
#pragma unroll
      for (int j = 0; j < 2; ++j) {
#pragma unroll
        for (int b = 0; b < 4; ++b) z[j][b] = U0[j][b] + U1[j][b];
        S256[j] = U0_256[j] + U1_256[j];
      }
      half_to_z2(z, S256, twHr, twHi, lane, pl0, plx);
      ifft256_2(z, twFr, twFi, Wr, Wi, lane);
      // lambda accumulate: LDS read-modify-write (psi layout, <=2-way banks)
#pragma unroll
      for (int a = 0; a < 4; ++a)
#pragma unroll
        for (int j = 0; j < 2; ++j) {
          f2 xa = stg[j][64 * a + lane];
          f2 cur = {lamL[j][psiE + 32 * a], lamL[j][psiE + 32 * a + 128]};
          f2 nv = cur + 0.001f * (xa - z[j][a] * (1.0f / 256.0f));
          lamL[j][psiE + 32 * a]       = nv.x;
          lamL[j][psiE + 32 * a + 128] = nv.y;
        }
      asm volatile("s_waitcnt lgkmcnt(0)" ::: "memory");
    }
  }

  // ---- final modes: half->z, ifft, pack to stage, float4 stores ----
  float4* o4 = (float4*)out;
#pragma unroll
  for (int j = 0; j < 2; ++j)
#pragma unroll
    for (int b = 0; b < 4; ++b) z[j][b] = U0[j][b];
  half_to_z2(z, U0_256, twHr, twHi, lane, pl0, plx);
  ifft256_2(z, twFr, twFi, Wr, Wi, lane);
  __syncthreads();   // all waves done reading x from stage
#pragma unroll
  for (int j = 0; j < 2; ++j)
#pragma unroll
    for (int a = 0; a < 4; ++a) stg[j][64 * a + lane] = z[j][a] * (1.0f / 256.0f);
  __syncthreads();
#pragma unroll
  for (int r = 0; r < 2; ++r) {
    const int n = tid + r * 256;
#pragma unroll
    for (int c = 0; c < 2; ++c) {
      float4 v;
      v.x = stage[(4 * c + 0) * 512 + n];
      v.y = stage[(4 * c + 1) * 512 + n];
      v.z = stage[(4 * c + 2) * 512 + n];
      v.w = stage[(4 * c + 3) * 512 + n];
      o4[FIELD / 4 + base4 + n * 32 + c] = v;
    }
  }
  __syncthreads();
#pragma unroll
  for (int j = 0; j < 2; ++j)
#pragma unroll
    for (int b = 0; b < 4; ++b) z[j][b] = U1[j][b];
  half_to_z2(z, U1_256, twHr, twHi, lane, pl0, plx);
  ifft256_2(z, twFr, twFi, Wr, Wi, lane);
#pragma unroll
  for (int j = 0; j < 2; ++j)
#pragma unroll
    for (int a = 0; a < 4; ++a) stg[j][64 * a + lane] = z[j][a] * (1.0f / 256.0f);
  __syncthreads();
#pragma unroll
  for (int r = 0; r < 2; ++r) {
    const int n = tid + r * 256;
#pragma unroll
    for (int c = 0; c < 2; ++c) {
      float4 v;
      v.x = stage[(4 * c + 0) * 512 + n];
      v.y = stage[(4 * c + 1) * 512 + n];
      v.z = stage[(4 * c + 2) * 512 + n];
      v.w = stage[(4 * c + 3) * 512 + n];
      o4[2 * FIELD / 4 + base4 + n * 32 + c] = v;
    }
  }

  if (lane == 0) {
    out[g0] = om0[0];            out[g0 + 1] = om0[1];
    out[NSEQ + g0] = om1[0];     out[NSEQ + g0 + 1] = om1[1];
  }
}

__global__ __launch_bounds__(128) void order_kernel(float* __restrict__ out) {
  const int bb = blockIdx.x;
  const int dd = threadIdx.x;
  float o0 = out[bb * 128 + dd];
  float o1 = out[NSEQ + bb * 128 + dd];
#pragma unroll
  for (int off = 32; off >= 1; off >>= 1) {
    o0 += __shfl_down(o0, off);
    o1 += __shfl_down(o1, off);
  }
  __shared__ float s0[2], s1[2];
  const int wv = dd >> 6;
  if ((dd & 63) == 0) { s0[wv] = o0; s1[wv] = o1; }
  __syncthreads();
  if (dd == 0) {
    const float a = s0[0] + s0[1];
    const float c = s1[0] + s1[1];
    out[2 * NSEQ + bb] = (a > c) ? 1.0f : 0.0f;
  }
}

__global__ __launch_bounds__(256) void swap_kernel(float* __restrict__ out) {
  const int idx = blockIdx.x * 256 + threadIdx.x;
  const int bb = idx >> 16;
  const float flag = out[2 * NSEQ + bb];
  if (flag > 0.5f) {
    const float p = out[FIELD + idx];
    const float r = out[2 * FIELD + idx];
    out[FIELD + idx] = r;
    out[2 * FIELD + idx] = p;
  }
}

extern "C" void kernel_launch(void* const* d_in, const int* in_sizes, int n_in,
                              void* d_out, int out_size, void* d_ws, size_t ws_size,
                              hipStream_t stream) {
  (void)in_sizes; (void)n_in; (void)d_ws; (void)ws_size; (void)out_size;
  const float* x = (const float*)d_in[0];
  float* out = (float*)d_out;
  vmd_kernel<<<512, 256, 0, stream>>>(x, out);
  order_kernel<<<32, 128, 0, stream>>>(out);
  swap_kernel<<<FIELD / 256, 256, 0, stream>>>(out);
  hipMemsetAsync(out, 0, (size_t)FIELD * sizeof(float), stream);
}

// Round 12
// 301.988 us; speedup vs baseline: 1.1249x; 1.1249x over previous
//
#include <hip/hip_runtime.h>
#include <math.h>

#define FIELD 2097152   // 32*512*128
#define NSEQ  4096      // 32*128 sequences

typedef float f2 __attribute__((ext_vector_type(2)));   // (re, im) -> VGPR pair

__device__ __forceinline__ f2 cmuli(f2 a)  { return (f2){-a.y, a.x}; }  //  i*a
__device__ __forceinline__ f2 cmulni(f2 a) { return (f2){a.y, -a.x}; }  // -i*a
__device__ __forceinline__ f2 conjf2(f2 a) { return (f2){a.x, -a.y}; }
__device__ __forceinline__ f2 cmul(f2 a, float c, float s) {   // a*(c+is)
  return c * a + s * cmuli(a);
}
__device__ __forceinline__ f2 cmulc(f2 a, float c, float s) {  // a*(c-is)
  return c * a - s * cmuli(a);
}

// ---- xor-lane exchange: DPP (VALU-speed, foldable) for h in {1,2,8},
// ---- ds_bpermute-based __shfl_xor otherwise. All 64 lanes active.
template<int CTRL>
__device__ __forceinline__ float dpp_f(float v) {
  return __int_as_float(__builtin_amdgcn_update_dpp(
      __float_as_int(v), __float_as_int(v), CTRL, 0xF, 0xF, true));
}
template<int H>
__device__ __forceinline__ float xlane(float v) {
  if constexpr (H == 1)      return dpp_f<0xB1>(v);    // quad_perm [1,0,3,2]
  else if constexpr (H == 2) return dpp_f<0x4E>(v);    // quad_perm [2,3,0,1]
  else if constexpr (H == 8) return dpp_f<0x128>(v);   // row_ror:8 (16-row xor8)
  else return __shfl_xor(v, H, 64);
}
template<int H>
__device__ __forceinline__ f2 xlane2(f2 v) {
  return (f2){xlane<H>(v.x), xlane<H>(v.y)};
}
__device__ __forceinline__ f2 shfl2(f2 v, int l) {
  return (f2){__shfl(v.x, l, 64), __shfl(v.y, l, 64)};
}
__device__ __forceinline__ float bcast0(float v) {   // lane0 broadcast via SALU
  return __int_as_float(__builtin_amdgcn_readfirstlane(__float_as_int(v)));
}

__device__ __forceinline__ void fft4_fwd(f2* v) {
  f2 t0 = v[0] + v[2], t1 = v[0] - v[2];
  f2 t2 = v[1] + v[3], t3 = v[1] - v[3];
  v[0] = t0 + t2; v[2] = t0 - t2;
  v[1] = t1 + cmulni(t3);
  v[3] = t1 + cmuli(t3);
}
__device__ __forceinline__ void fft4_inv(f2* v) {
  f2 t0 = v[0] + v[2], t1 = v[0] - v[2];
  f2 t2 = v[1] + v[3], t3 = v[1] - v[3];
  v[0] = t0 + t2; v[2] = t0 - t2;
  v[1] = t1 + cmuli(t3);
  v[3] = t1 + cmulni(t3);
}

template<int H>
__device__ __forceinline__ void fwd_stage(f2* v, float wr, float wi, int lane) {
  const bool hi = (lane & H) != 0;
  const float sg = hi ? -1.0f : 1.0f;
#pragma unroll
  for (int b = 0; b < 4; ++b) {
    f2 p = xlane2<H>(v[b]);
    f2 t = sg * v[b] + p;
    f2 m = cmul(t, wr, wi);
    v[b] = hi ? m : t;
  }
}
template<int H>
__device__ __forceinline__ void inv_stage(f2* v, float wr, float wi, int lane) {
  const bool hi = (lane & H) != 0;
  const float sg = hi ? -1.0f : 1.0f;
#pragma unroll
  for (int b = 0; b < 4; ++b) {
    f2 p = xlane2<H>(v[b]);
    f2 q = hi ? v[b] : p;     // operand multiplied by conj(W)
    f2 r = hi ? p : v[b];     // operand added
    f2 t = cmulc(q, wr, wi);
    v[b] = sg * t + r;
  }
}

// 256-point FFT: time n = 64a+lane (slot a) <-> freq k = 4*rev6(lane)+b.
__device__ __forceinline__ void fft256_fwd(f2* v,
                                           const float* twFr, const float* twFi,
                                           const float* Wr, const float* Wi,
                                           int lane) {
  fft4_fwd(v);
#pragma unroll
  for (int b = 1; b < 4; ++b) v[b] = cmul(v[b], twFr[b-1], twFi[b-1]);
  fwd_stage<32>(v, Wr[0], Wi[0], lane);
  fwd_stage<16>(v, Wr[1], Wi[1], lane);
  fwd_stage<8> (v, Wr[2], Wi[2], lane);
  fwd_stage<4> (v, Wr[3], Wi[3], lane);
  fwd_stage<2> (v, Wr[4], Wi[4], lane);
  fwd_stage<1> (v, Wr[5], Wi[5], lane);
}

__device__ __forceinline__ void ifft256(f2* v,
                                        const float* twFr, const float* twFi,
                                        const float* Wr, const float* Wi,
                                        int lane) {
  inv_stage<1> (v, Wr[5], Wi[5], lane);
  inv_stage<2> (v, Wr[4], Wi[4], lane);
  inv_stage<4> (v, Wr[3], Wi[3], lane);
  inv_stage<8> (v, Wr[2], Wi[2], lane);
  inv_stage<16>(v, Wr[1], Wi[1], lane);
  inv_stage<32>(v, Wr[0], Wi[0], lane);
#pragma unroll
  for (int b = 1; b < 4; ++b) v[b] = cmulc(v[b], twFr[b-1], twFi[b-1]);
  fft4_inv(v);
}

// Half-spectrum S[0..255] (+ real scalar S256) -> packed Z for ifft256.
__device__ __forceinline__ void half_to_z(f2* S, float S256,
                                          const float* twHr, const float* twHi,
                                          int lane, int pl0, int plx) {
  f2 P[4];
  P[0] = shfl2(S[0], pl0);
#pragma unroll
  for (int b = 1; b < 4; ++b) P[b] = shfl2(S[4 - b], plx);
  P[0] = (lane == 0) ? (f2){S256, 0.0f} : P[0];
#pragma unroll
  for (int b = 0; b < 4; ++b) {
    f2 cP = conjf2(P[b]);
    f2 A = 0.5f * (S[b] + cP);
    f2 B = 0.5f * (S[b] - cP);
    f2 Bt = cmul(B, twHr[b], twHi[b]);
    S[b] = A + cmuli(Bt);
  }
}

// Per-bin mode update exploiting Hermitian symmetry (no cross-lane ops).
__device__ __forceinline__ void mode_update4(const f2* X, const f2* V, f2* U,
                                             const float* lam1, const float* lam2,
                                             float om, float f0) {
#pragma unroll
  for (int b = 0; b < 4; ++b) {
    float f = f0 + (float)b * (1.0f / 512.0f);
    float dfp = f - om;
    float dfm = f + om;
    float gp = __builtin_amdgcn_rcpf(fmaf(1600.0f * dfp, dfp, 1.0f));
    float gm = __builtin_amdgcn_rcpf(fmaf(1600.0f * dfm, dfm, 1.0f));
    float gs = 0.5f * (gp + gm);
    f2 D = X[b] - V[b];
    float lt = 0.25f * fmaf(lam1[b], gp, lam2[b] * gm);
    U[b] = gs * D + (f2){lt, 0.0f};
  }
}

// One wave per (b,d) sequence (round-10 structure: best clean baseline).
// DPP xor-lane for h in {1,2,8} converts half the shuffle stages from
// ds_bpermute (DS pipe, ~30+ cyc latency) to VALU-speed dpp moves.
__global__ __attribute__((amdgpu_flat_work_group_size(256, 256),
                          amdgpu_waves_per_eu(4, 4),
                          amdgpu_num_vgpr(96)))
void vmd_kernel(const float* __restrict__ x, float* __restrict__ out) {
  __shared__ float stage[4 * 512];    // [seq][n]; x resident during loop, reused for out
  __shared__ float ldsLam[4 * 512];   // psi-permuted lambda per wave

  const int tid = threadIdx.x;
  const int wv = tid >> 6;
  const int lane = tid & 63;
  const int w = (blockIdx.x >> 3) + ((blockIdx.x & 7) << 7);   // XCD swizzle
  const int g = 4 * w + wv;
  const int bb = w >> 5;
  const int d0 = (4 * w) & 127;
  const int base4 = bb * 16384 + (d0 >> 2);
  float* lamLds = ldsLam + wv * 512;
  f2* stg2 = (f2*)stage + wv * 256;   // packed (even,odd) pair view of this seq

  const int rev = (int)(__brev((unsigned)lane) >> 26);           // rev6(lane)
  const float f0 = (float)rev * (1.0f / 128.0f);
  const int plx = lane ^ 63;
  const int pl0 = (int)(__brev((unsigned)((64 - rev) & 63)) >> 26);

  float Wr[6], Wi[6];
#pragma unroll
  for (int s = 0; s < 6; ++s) {
    const int h = 32 >> s;
    float th = (float)(lane & (h - 1)) * (3.14159265358979323846f / (float)h);
    float sn, cs; sincosf(th, &sn, &cs);
    Wr[s] = cs; Wi[s] = -sn;
  }
  float twFr[3], twFi[3];
#pragma unroll
  for (int b = 1; b < 4; ++b) {
    float th = (float)(lane * b) * 0.02454369260617026f;   // 2pi/256
    float sn, cs; sincosf(th, &sn, &cs);
    twFr[b-1] = cs; twFi[b-1] = -sn;
  }
  float twHr[4], twHi[4];
#pragma unroll
  for (int b = 0; b < 4; ++b) {
    float th = (float)(4 * rev + b) * 0.01227184630308513f; // 2pi/512
    float sn, cs; sincosf(th, &sn, &cs);
    twHr[b] = cs; twHi[b] = sn;
  }

  // ---- load x: float4 (n, d0..d0+3) -> stage[seq][n]; zero lambda ----
  {
    const float4* x4 = (const float4*)x;
    float4 va = x4[base4 + tid * 32];
    float4 vb = x4[base4 + (tid + 256) * 32];
    stage[tid]        = va.x; stage[512 + tid]        = va.y;
    stage[1024 + tid] = va.z; stage[1536 + tid]       = va.w;
    stage[tid + 256]        = vb.x; stage[512 + tid + 256]  = vb.y;
    stage[1024 + tid + 256] = vb.z; stage[1536 + tid + 256] = vb.w;
#pragma unroll
    for (int j = 0; j < 8; ++j) ldsLam[tid * 8 + j] = 0.0f;
  }
  __syncthreads();

  // ---- initial FFT input straight from LDS (x stays resident in stage) ----
  f2 z[4];
#pragma unroll
  for (int a = 0; a < 4; ++a) z[a] = stg2[64 * a + lane];
  fft256_fwd(z, twFr, twFi, Wr, Wi, lane);
  f2 X[4];
  float X256;
  {
    f2 P[4];
    P[0] = shfl2(z[0], pl0);
#pragma unroll
    for (int b = 1; b < 4; ++b) P[b] = shfl2(z[4 - b], plx);
    X256 = bcast0(z[0].x - z[0].y);
#pragma unroll
    for (int b = 0; b < 4; ++b) {
      f2 cP = conjf2(P[b]);
      f2 E = 0.5f * (z[b] + cP);
      f2 O = 0.5f * cmulni(z[b] - cP);
      X[b] = E + cmulc(O, twHr[b], twHi[b]);
    }
  }

  f2 U0[4], U1[4], lam[4];
#pragma unroll
  for (int b = 0; b < 4; ++b) {
    U0[b] = (f2){0.0f, 0.0f}; U1[b] = (f2){0.0f, 0.0f};
    lam[b] = (f2){0.0f, 0.0f};
  }
  float U0_256 = 0.0f, U1_256 = 0.0f;
  float om0 = 0.0f, om1 = 0.0f;

  const int psiE = 256 * (lane & 1) + (lane >> 1);   // lambda write base

#pragma unroll 1
  for (int it = 0; it < 50; ++it) {
    // lambda reads (psi layout): lam1[b]=lam[k+256], lam2[b]=lam[256-k]
    float lam1[4], lam2[4];
#pragma unroll
    for (int b = 0; b < 4; ++b) lam1[b] = lamLds[128 * b + 64 + rev];
    lam2[0] = lamLds[64 - rev];
#pragma unroll
    for (int b = 1; b < 4; ++b) lam2[b] = lamLds[128 * (4 - b) + 63 - rev];
    float lam0 = lamLds[0];

    mode_update4(X, U1, U0, lam1, lam2, om0, f0);
    {
      float dm = 0.5f + om0;
      float gg = __builtin_amdgcn_rcpf(fmaf(1600.0f * dm, dm, 1.0f));
      U0_256 = (X256 - U1_256 + 0.5f * lam0) * gg;
    }
    mode_update4(X, U0, U1, lam1, lam2, om1, f0);
    {
      float dm = 0.5f + om1;
      float gg = __builtin_amdgcn_rcpf(fmaf(1600.0f * dm, dm, 1.0f));
      U1_256 = (X256 - U0_256 + 0.5f * lam0) * gg;
    }

    // omega: packed (num,den) pairs; DPP for the 8/2/1 reduce steps
    f2 s0 = (f2){0.0f, 0.0f}, s1 = (f2){0.0f, 0.0f};
#pragma unroll
    for (int b = 0; b < 4; ++b) {
      float f = f0 + (float)b * (1.0f / 512.0f);
      float p0 = fmaf(U0[b].x, U0[b].x, U0[b].y * U0[b].y);
      float p1 = fmaf(U1[b].x, U1[b].x, U1[b].y * U1[b].y);
      s0 = s0 + (f2){f * p0, p0};
      s1 = s1 + (f2){f * p1, p1};
    }
    s0 = s0 + xlane2<32>(s0);  s1 = s1 + xlane2<32>(s1);
    s0 = s0 + xlane2<16>(s0);  s1 = s1 + xlane2<16>(s1);
    s0 = s0 + xlane2<8>(s0);   s1 = s1 + xlane2<8>(s1);
    s0 = s0 + xlane2<4>(s0);   s1 = s1 + xlane2<4>(s1);
    s0 = s0 + xlane2<2>(s0);   s1 = s1 + xlane2<2>(s1);
    s0 = s0 + xlane2<1>(s0);   s1 = s1 + xlane2<1>(s1);
    om0 = s0.x / (s0.y + 1e-7f);
    om1 = s1.x / (s1.y + 1e-7f);

    if (it < 49) {   // last iteration's lambda is never consumed
#pragma unroll
      for (int b = 0; b < 4; ++b) z[b] = U0[b] + U1[b];
      float S256 = U0_256 + U1_256;
      half_to_z(z, S256, twHr, twHi, lane, pl0, plx);
      ifft256(z, twFr, twFi, Wr, Wi, lane);
#pragma unroll
      for (int a = 0; a < 4; ++a) {
        f2 xa = stg2[64 * a + lane];               // x from LDS
        lam[a] = lam[a] + 0.001f * (xa - z[a] * (1.0f / 256.0f));
        lamLds[psiE + 32 * a]       = lam[a].x;
        lamLds[psiE + 32 * a + 128] = lam[a].y;
      }
      asm volatile("s_waitcnt lgkmcnt(0)" ::: "memory");
    }
  }

  // ---- final modes: half->z, ifft256, pack to stage, float4 stores ----
  float4* o4 = (float4*)out;
#pragma unroll
  for (int b = 0; b < 4; ++b) z[b] = U0[b];
  half_to_z(z, U0_256, twHr, twHi, lane, pl0, plx);
  ifft256(z, twFr, twFi, Wr, Wi, lane);
  __syncthreads();   // all waves done reading x from stage
#pragma unroll
  for (int a = 0; a < 4; ++a) stg2[64 * a + lane] = z[a] * (1.0f / 256.0f);
  __syncthreads();
#pragma unroll
  for (int r = 0; r < 2; ++r) {
    const int n = tid + r * 256;
    float4 v;
    v.x = stage[n]; v.y = stage[512 + n]; v.z = stage[1024 + n]; v.w = stage[1536 + n];
    o4[FIELD / 4 + base4 + n * 32] = v;
  }
  __syncthreads();
#pragma unroll
  for (int b = 0; b < 4; ++b) z[b] = U1[b];
  half_to_z(z, U1_256, twHr, twHi, lane, pl0, plx);
  ifft256(z, twFr, twFi, Wr, Wi, lane);
#pragma unroll
  for (int a = 0; a < 4; ++a) stg2[64 * a + lane] = z[a] * (1.0f / 256.0f);
  __syncthreads();
#pragma unroll
  for (int r = 0; r < 2; ++r) {
    const int n = tid + r * 256;
    float4 v;
    v.x = stage[n]; v.y = stage[512 + n]; v.z = stage[1024 + n]; v.w = stage[1536 + n];
    o4[2 * FIELD / 4 + base4 + n * 32] = v;
  }

  if (lane == 0) {
    out[g] = om0;            // staged in trend region (zeroed later)
    out[NSEQ + g] = om1;
  }
}

__global__ __launch_bounds__(128) void order_kernel(float* __restrict__ out) {
  const int bb = blockIdx.x;
  const int dd = threadIdx.x;
  float o0 = out[bb * 128 + dd];
  float o1 = out[NSEQ + bb * 128 + dd];
#pragma unroll
  for (int off = 32; off >= 1; off >>= 1) {
    o0 += __shfl_down(o0, off);
    o1 += __shfl_down(o1, off);
  }
  __shared__ float s0[2], s1[2];
  const int wv = dd >> 6;
  if ((dd & 63) == 0) { s0[wv] = o0; s1[wv] = o1; }
  __syncthreads();
  if (dd == 0) {
    const float a = s0[0] + s0[1];
    const float c = s1[0] + s1[1];
    out[2 * NSEQ + bb] = (a > c) ? 1.0f : 0.0f;
  }
}

__global__ __launch_bounds__(256) void swap_kernel(float* __restrict__ out) {
  const int idx = blockIdx.x * 256 + threadIdx.x;
  const int bb = idx >> 16;
  const float flag = out[2 * NSEQ + bb];
  if (flag > 0.5f) {
    const float p = out[FIELD + idx];
    const float r = out[2 * FIELD + idx];
    out[FIELD + idx] = r;
    out[2 * FIELD + idx] = p;
  }
}

extern "C" void kernel_launch(void* const* d_in, const int* in_sizes, int n_in,
                              void* d_out, int out_size, void* d_ws, size_t ws_size,
                              hipStream_t stream) {
  (void)in_sizes; (void)n_in; (void)d_ws; (void)ws_size; (void)out_size;
  const float* x = (const float*)d_in[0];
  float* out = (float*)d_out;
  vmd_kernel<<<NSEQ / 4, 256, 0, stream>>>(x, out);
  order_kernel<<<32, 128, 0, stream>>>(out);
  swap_kernel<<<FIELD / 256, 256, 0, stream>>>(out);
  hipMemsetAsync(out, 0, (size_t)FIELD * sizeof(float), stream);
}

// Round 13
// 256.694 us; speedup vs baseline: 1.3234x; 1.1765x over previous
//
#include <hip/hip_runtime.h>
#include <math.h>

#define FIELD 2097152   // 32*512*128
#define NSEQ  4096      // 32*128 sequences

typedef float f2 __attribute__((ext_vector_type(2)));   // (re, im) -> VGPR pair

__device__ __forceinline__ f2 swp(f2 a) { return __builtin_shufflevector(a, a, 1, 0); }
__device__ __forceinline__ f2 conjf2(f2 a) { return (f2){a.x, -a.y}; }
// multiply by (c + i s), with ns = (-s, s): 1 pk_mul + 1 pk_fma (swap -> op_sel)
__device__ __forceinline__ f2 cmulp(f2 a, float c, f2 ns)  { return c * a + ns * swp(a); }
// multiply by (c - i s)
__device__ __forceinline__ f2 cmulpc(f2 a, float c, f2 ns) { return c * a - ns * swp(a); }
// a + i*b  /  a - i*b
__device__ __forceinline__ f2 addi(f2 a, f2 b) { return a + (f2){-1.0f, 1.0f} * swp(b); }
__device__ __forceinline__ f2 subi(f2 a, f2 b) { return a + (f2){1.0f, -1.0f} * swp(b); }

// ---- xor-lane exchange: DPP (VALU-speed) for h in {1,2,8}; shfl otherwise.
template<int CTRL>
__device__ __forceinline__ float dpp_f(float v) {
  return __int_as_float(__builtin_amdgcn_update_dpp(
      __float_as_int(v), __float_as_int(v), CTRL, 0xF, 0xF, true));
}
template<int H>
__device__ __forceinline__ float xlane(float v) {
  if constexpr (H == 1)      return dpp_f<0xB1>(v);    // quad_perm [1,0,3,2]
  else if constexpr (H == 2) return dpp_f<0x4E>(v);    // quad_perm [2,3,0,1]
  else if constexpr (H == 8) return dpp_f<0x128>(v);   // row_ror:8 (xor8 in 16-row)
  else return __shfl_xor(v, H, 64);
}
template<int H>
__device__ __forceinline__ f2 xlane2(f2 v) {
  return (f2){xlane<H>(v.x), xlane<H>(v.y)};
}
__device__ __forceinline__ f2 shfl2(f2 v, int l) {
  return (f2){__shfl(v.x, l, 64), __shfl(v.y, l, 64)};
}
__device__ __forceinline__ float bcast0(float v) {
  return __int_as_float(__builtin_amdgcn_readfirstlane(__float_as_int(v)));
}

__device__ __forceinline__ void fft4_fwd(f2* v) {
  f2 t0 = v[0] + v[2], t1 = v[0] - v[2];
  f2 t2 = v[1] + v[3], t3 = v[1] - v[3];
  v[0] = t0 + t2; v[2] = t0 - t2;
  v[1] = subi(t1, t3);
  v[3] = addi(t1, t3);
}
__device__ __forceinline__ void fft4_inv(f2* v) {
  f2 t0 = v[0] + v[2], t1 = v[0] - v[2];
  f2 t2 = v[1] + v[3], t3 = v[1] - v[3];
  v[0] = t0 + t2; v[2] = t0 - t2;
  v[1] = addi(t1, t3);
  v[3] = subi(t1, t3);
}

// Butterfly stages with LANE-MASKED twiddles (lo lanes hold W=(1,0), so no
// cndmask select is needed anywhere; identical algebra verified vs the
// select-based form). sg = +1 lo / -1 hi.
template<int H>
__device__ __forceinline__ void fwd_stage(f2* v, float wr, f2 wn, float sg) {
#pragma unroll
  for (int b = 0; b < 4; ++b) {
    f2 p = xlane2<H>(v[b]);
    f2 t = sg * v[b] + p;          // lo: v+p ; hi: p-v
    v[b] = cmulp(t, wr, wn);       // lo: *1 ; hi: *e^{-i th}
  }
}
template<int H>
__device__ __forceinline__ void inv_stage(f2* v, float wr, f2 wn, float sg) {
#pragma unroll
  for (int b = 0; b < 4; ++b) {
    f2 u = cmulpc(v[b], wr, wn);   // lo: v ; hi: v*e^{+i th} (conj W)
    f2 p = xlane2<H>(u);
    v[b] = sg * u + p;             // lo: u+p ; hi: p-u
  }
}

// 256-point FFT: time n = 64a+lane (slot a) <-> freq k = 4*rev6(lane)+b.
__device__ __forceinline__ void fft256_fwd(f2* v,
                                           const float* twFc, const f2* twFn,
                                           const float* wrS, const f2* wnS,
                                           const float* sgS) {
  fft4_fwd(v);
#pragma unroll
  for (int b = 1; b < 4; ++b) v[b] = cmulp(v[b], twFc[b-1], twFn[b-1]);
  fwd_stage<32>(v, wrS[0], wnS[0], sgS[0]);
  fwd_stage<16>(v, wrS[1], wnS[1], sgS[1]);
  fwd_stage<8> (v, wrS[2], wnS[2], sgS[2]);
  fwd_stage<4> (v, wrS[3], wnS[3], sgS[3]);
  fwd_stage<2> (v, wrS[4], wnS[4], sgS[4]);
  fwd_stage<1> (v, wrS[5], wnS[5], sgS[5]);
}

__device__ __forceinline__ void ifft256(f2* v,
                                        const float* twFc, const f2* twFn,
                                        const float* wrS, const f2* wnS,
                                        const float* sgS) {
  inv_stage<1> (v, wrS[5], wnS[5], sgS[5]);
  inv_stage<2> (v, wrS[4], wnS[4], sgS[4]);
  inv_stage<4> (v, wrS[3], wnS[3], sgS[3]);
  inv_stage<8> (v, wrS[2], wnS[2], sgS[2]);
  inv_stage<16>(v, wrS[1], wnS[1], sgS[1]);
  inv_stage<32>(v, wrS[0], wnS[0], sgS[0]);
#pragma unroll
  for (int b = 1; b < 4; ++b) v[b] = cmulpc(v[b], twFc[b-1], twFn[b-1]);
  fft4_inv(v);
}

// Half-spectrum S[0..255] (+ real scalar S256) -> packed Z for ifft256.
// twH = e^{+2pi i k/512}: c=twHc, ns=twHn=(-sin, sin).
__device__ __forceinline__ void half_to_z(f2* S, float S256,
                                          const float* twHc, const f2* twHn,
                                          int lane, int pl0, int plx) {
  f2 P[4];
  P[0] = shfl2(S[0], pl0);
#pragma unroll
  for (int b = 1; b < 4; ++b) P[b] = shfl2(S[4 - b], plx);
  P[0] = (lane == 0) ? (f2){S256, 0.0f} : P[0];
#pragma unroll
  for (int b = 0; b < 4; ++b) {
    f2 cP = conjf2(P[b]);
    f2 A = 0.5f * (S[b] + cP);
    f2 B = 0.5f * (S[b] - cP);
    f2 Bt = cmulp(B, twHc[b], twHn[b]);   // B * e^{+i th}
    S[b] = addi(A, Bt);
  }
}

// Per-bin mode update exploiting Hermitian symmetry (no cross-lane ops).
__device__ __forceinline__ void mode_update4(const f2* X, const f2* V, f2* U,
                                             const float* lam1, const float* lam2,
                                             float om, float f0) {
#pragma unroll
  for (int b = 0; b < 4; ++b) {
    float f = f0 + (float)b * (1.0f / 512.0f);
    float dfp = f - om;
    float dfm = f + om;
    float gp = __builtin_amdgcn_rcpf(fmaf(1600.0f * dfp, dfp, 1.0f));
    float gm = __builtin_amdgcn_rcpf(fmaf(1600.0f * dfm, dfm, 1.0f));
    float gs = 0.5f * (gp + gm);
    f2 D = X[b] - V[b];
    float lt = 0.25f * fmaf(lam1[b], gp, lam2[b] * gm);
    U[b] = gs * D + (f2){lt, 0.0f};
  }
}

// One wave per (b,d) sequence. Lane-masked twiddles (no cndmask in FFT),
// pk-packed complex mul, DPP xor-lane for h in {1,2,8}.
__global__ __attribute__((amdgpu_flat_work_group_size(256, 256),
                          amdgpu_waves_per_eu(4, 4),
                          amdgpu_num_vgpr(96)))
void vmd_kernel(const float* __restrict__ x, float* __restrict__ out) {
  __shared__ float stage[4 * 512];    // [seq][n]; x resident during loop, reused for out
  __shared__ float ldsLam[4 * 512];   // psi-permuted lambda per wave

  const int tid = threadIdx.x;
  const int wv = tid >> 6;
  const int lane = tid & 63;
  const int w = (blockIdx.x >> 3) + ((blockIdx.x & 7) << 7);   // XCD swizzle
  const int g = 4 * w + wv;
  const int bb = w >> 5;
  const int d0 = (4 * w) & 127;
  const int base4 = bb * 16384 + (d0 >> 2);
  float* lamLds = ldsLam + wv * 512;
  f2* stg2 = (f2*)stage + wv * 256;   // packed (even,odd) pair view of this seq

  const int rev = (int)(__brev((unsigned)lane) >> 26);           // rev6(lane)
  const float f0 = (float)rev * (1.0f / 128.0f);
  const int plx = lane ^ 63;
  const int pl0 = (int)(__brev((unsigned)((64 - rev) & 63)) >> 26);

  // Stage twiddles, lane-masked: lo lanes = identity (wr=1, wn=0).
  float wrS[6], sgS[6]; f2 wnS[6];
#pragma unroll
  for (int s = 0; s < 6; ++s) {
    const int h = 32 >> s;
    const bool hi = (lane & h) != 0;
    float th = (float)(lane & (h - 1)) * (3.14159265358979323846f / (float)h);
    float sn, cs; sincosf(th, &sn, &cs);
    wrS[s] = hi ? cs : 1.0f;                       // W = e^{-i th}: c=cs, s=-sn
    wnS[s] = hi ? (f2){sn, -sn} : (f2){0.0f, 0.0f}; // ns = (-s, s) = (sn, -sn)
    sgS[s] = hi ? -1.0f : 1.0f;
  }
  float twFc[3]; f2 twFn[3];
#pragma unroll
  for (int b = 1; b < 4; ++b) {
    float th = (float)(lane * b) * 0.02454369260617026f;   // 2pi/256, e^{-i th}
    float sn, cs; sincosf(th, &sn, &cs);
    twFc[b-1] = cs; twFn[b-1] = (f2){sn, -sn};
  }
  float twHc[4]; f2 twHn[4];
#pragma unroll
  for (int b = 0; b < 4; ++b) {
    float th = (float)(4 * rev + b) * 0.01227184630308513f; // 2pi/512, e^{+i th}
    float sn, cs; sincosf(th, &sn, &cs);
    twHc[b] = cs; twHn[b] = (f2){-sn, sn};
  }

  // ---- load x: float4 (n, d0..d0+3) -> stage[seq][n]; zero lambda ----
  {
    const float4* x4 = (const float4*)x;
    float4 va = x4[base4 + tid * 32];
    float4 vb = x4[base4 + (tid + 256) * 32];
    stage[tid]        = va.x; stage[512 + tid]        = va.y;
    stage[1024 + tid] = va.z; stage[1536 + tid]       = va.w;
    stage[tid + 256]        = vb.x; stage[512 + tid + 256]  = vb.y;
    stage[1024 + tid + 256] = vb.z; stage[1536 + tid + 256] = vb.w;
#pragma unroll
    for (int j = 0; j < 8; ++j) ldsLam[tid * 8 + j] = 0.0f;
  }
  __syncthreads();

  // ---- initial FFT input straight from LDS (x stays resident in stage) ----
  f2 z[4];
#pragma unroll
  for (int a = 0; a < 4; ++a) z[a] = stg2[64 * a + lane];
  fft256_fwd(z, twFc, twFn, wrS, wnS, sgS);
  f2 X[4];
  float X256;
  {
    f2 P[4];
    P[0] = shfl2(z[0], pl0);
#pragma unroll
    for (int b = 1; b < 4; ++b) P[b] = shfl2(z[4 - b], plx);
    X256 = bcast0(z[0].x - z[0].y);
#pragma unroll
    for (int b = 0; b < 4; ++b) {
      f2 cP = conjf2(P[b]);
      f2 E = 0.5f * (z[b] + cP);
      f2 O = 0.5f * (f2){1.0f, -1.0f} * swp(z[b] - cP);   // -i*(z-cP)/2
      X[b] = E + cmulpc(O, twHc[b], twHn[b]);             // O * e^{-i th}
    }
  }

  f2 U0[4], U1[4], lam[4];
#pragma unroll
  for (int b = 0; b < 4; ++b) {
    U0[b] = (f2){0.0f, 0.0f}; U1[b] = (f2){0.0f, 0.0f};
    lam[b] = (f2){0.0f, 0.0f};
  }
  float U0_256 = 0.0f, U1_256 = 0.0f;
  float om0 = 0.0f, om1 = 0.0f;

  const int psiE = 256 * (lane & 1) + (lane >> 1);   // lambda write base

#pragma unroll 1
  for (int it = 0; it < 50; ++it) {
    // lambda reads (psi layout): lam1[b]=lam[k+256], lam2[b]=lam[256-k]
    float lam1[4], lam2[4];
#pragma unroll
    for (int b = 0; b < 4; ++b) lam1[b] = lamLds[128 * b + 64 + rev];
    lam2[0] = lamLds[64 - rev];
#pragma unroll
    for (int b = 1; b < 4; ++b) lam2[b] = lamLds[128 * (4 - b) + 63 - rev];
    float lam0 = lamLds[0];

    mode_update4(X, U1, U0, lam1, lam2, om0, f0);
    {
      float dm = 0.5f + om0;
      float gg = __builtin_amdgcn_rcpf(fmaf(1600.0f * dm, dm, 1.0f));
      U0_256 = (X256 - U1_256 + 0.5f * lam0) * gg;
    }
    mode_update4(X, U0, U1, lam1, lam2, om1, f0);
    {
      float dm = 0.5f + om1;
      float gg = __builtin_amdgcn_rcpf(fmaf(1600.0f * dm, dm, 1.0f));
      U1_256 = (X256 - U0_256 + 0.5f * lam0) * gg;
    }

    // omega: packed (num,den) pairs; DPP for the 8/2/1 reduce steps
    f2 s0 = (f2){0.0f, 0.0f}, s1 = (f2){0.0f, 0.0f};
#pragma unroll
    for (int b = 0; b < 4; ++b) {
      float f = f0 + (float)b * (1.0f / 512.0f);
      float p0 = fmaf(U0[b].x, U0[b].x, U0[b].y * U0[b].y);
      float p1 = fmaf(U1[b].x, U1[b].x, U1[b].y * U1[b].y);
      s0 = s0 + (f2){f * p0, p0};
      s1 = s1 + (f2){f * p1, p1};
    }
    s0 = s0 + xlane2<32>(s0);  s1 = s1 + xlane2<32>(s1);
    s0 = s0 + xlane2<16>(s0);  s1 = s1 + xlane2<16>(s1);
    s0 = s0 + xlane2<8>(s0);   s1 = s1 + xlane2<8>(s1);
    s0 = s0 + xlane2<4>(s0);   s1 = s1 + xlane2<4>(s1);
    s0 = s0 + xlane2<2>(s0);   s1 = s1 + xlane2<2>(s1);
    s0 = s0 + xlane2<1>(s0);   s1 = s1 + xlane2<1>(s1);
    om0 = s0.x / (s0.y + 1e-7f);
    om1 = s1.x / (s1.y + 1e-7f);

    if (it < 49) {   // last iteration's lambda is never consumed
#pragma unroll
      for (int b = 0; b < 4; ++b) z[b] = U0[b] + U1[b];
      float S256 = U0_256 + U1_256;
      half_to_z(z, S256, twHc, twHn, lane, pl0, plx);
      ifft256(z, twFc, twFn, wrS, wnS, sgS);
#pragma unroll
      for (int a = 0; a < 4; ++a) {
        f2 xa = stg2[64 * a + lane];               // x from LDS
        lam[a] = lam[a] + 0.001f * (xa - z[a] * (1.0f / 256.0f));
        lamLds[psiE + 32 * a]       = lam[a].x;
        lamLds[psiE + 32 * a + 128] = lam[a].y;
      }
      asm volatile("s_waitcnt lgkmcnt(0)" ::: "memory");
    }
  }

  // ---- final modes: half->z, ifft256, pack to stage, float4 stores ----
  float4* o4 = (float4*)out;
#pragma unroll
  for (int b = 0; b < 4; ++b) z[b] = U0[b];
  half_to_z(z, U0_256, twHc, twHn, lane, pl0, plx);
  ifft256(z, twFc, twFn, wrS, wnS, sgS);
  __syncthreads();   // all waves done reading x from stage
#pragma unroll
  for (int a = 0; a < 4; ++a) stg2[64 * a + lane] = z[a] * (1.0f / 256.0f);
  __syncthreads();
#pragma unroll
  for (int r = 0; r < 2; ++r) {
    const int n = tid + r * 256;
    float4 v;
    v.x = stage[n]; v.y = stage[512 + n]; v.z = stage[1024 + n]; v.w = stage[1536 + n];
    o4[FIELD / 4 + base4 + n * 32] = v;
  }
  __syncthreads();
#pragma unroll
  for (int b = 0; b < 4; ++b) z[b] = U1[b];
  half_to_z(z, U1_256, twHc, twHn, lane, pl0, plx);
  ifft256(z, twFc, twFn, wrS, wnS, sgS);
#pragma unroll
  for (int a = 0; a < 4; ++a) stg2[64 * a + lane] = z[a] * (1.0f / 256.0f);
  __syncthreads();
#pragma unroll
  for (int r = 0; r < 2; ++r) {
    const int n = tid + r * 256;
    float4 v;
    v.x = stage[n]; v.y = stage[512 + n]; v.z = stage[1024 + n]; v.w = stage[1536 + n];
    o4[2 * FIELD / 4 + base4 + n * 32] = v;
  }

  if (lane == 0) {
    out[g] = om0;            // staged in trend region (zeroed later)
    out[NSEQ + g] = om1;
  }
}

__global__ __launch_bounds__(128) void order_kernel(float* __restrict__ out) {
  const int bb = blockIdx.x;
  const int dd = threadIdx.x;
  float o0 = out[bb * 128 + dd];
  float o1 = out[NSEQ + bb * 128 + dd];
#pragma unroll
  for (int off = 32; off >= 1; off >>= 1) {
    o0 += __shfl_down(o0, off);
    o1 += __shfl_down(o1, off);
  }
  __shared__ float s0[2], s1[2];
  const int wv = dd >> 6;
  if ((dd & 63) == 0) { s0[wv] = o0; s1[wv] = o1; }
  __syncthreads();
  if (dd == 0) {
    const float a = s0[0] + s0[1];
    const float c = s1[0] + s1[1];
    out[2 * NSEQ + bb] = (a > c) ? 1.0f : 0.0f;
  }
}

__global__ __launch_bounds__(256) void swap_kernel(float* __restrict__ out) {
  const int idx = blockIdx.x * 256 + threadIdx.x;
  const int bb = idx >> 16;
  const float flag = out[2 * NSEQ + bb];
  if (flag > 0.5f) {
    const float p = out[FIELD + idx];
    const float r = out[2 * FIELD + idx];
    out[FIELD + idx] = r;
    out[2 * FIELD + idx] = p;
  }
}

extern "C" void kernel_launch(void* const* d_in, const int* in_sizes, int n_in,
                              void* d_out, int out_size, void* d_ws, size_t ws_size,
                              hipStream_t stream) {
  (void)in_sizes; (void)n_in; (void)d_ws; (void)ws_size; (void)out_size;
  const float* x = (const float*)d_in[0];
  float* out = (float*)d_out;
  vmd_kernel<<<NSEQ / 4, 256, 0, stream>>>(x, out);
  order_kernel<<<32, 128, 0, stream>>>(out);
  swap_kernel<<<FIELD / 256, 256, 0, stream>>>(out);
  hipMemsetAsync(out, 0, (size_t)FIELD * sizeof(float), stream);
}

// Round 15
// 251.556 us; speedup vs baseline: 1.3504x; 1.0204x over previous
//
#include <hip/hip_runtime.h>
#include <math.h>

#define FIELD 2097152   // 32*512*128
#define NSEQ  4096      // 32*128 sequences

typedef float f2 __attribute__((ext_vector_type(2)));   // (re, im) -> VGPR pair

__device__ __forceinline__ f2 swp(f2 a) { return __builtin_shufflevector(a, a, 1, 0); }
__device__ __forceinline__ f2 conjf2(f2 a) { return (f2){a.x, -a.y}; }
// multiply by (c + i s), with ns = (-s, s): 1 pk_mul + 1 pk_fma (swap -> op_sel)
__device__ __forceinline__ f2 cmulp(f2 a, float c, f2 ns)  { return c * a + ns * swp(a); }
// multiply by (c - i s)
__device__ __forceinline__ f2 cmulpc(f2 a, float c, f2 ns) { return c * a - ns * swp(a); }
// a + i*b  /  a - i*b
__device__ __forceinline__ f2 addi(f2 a, f2 b) { return a + (f2){-1.0f, 1.0f} * swp(b); }
__device__ __forceinline__ f2 subi(f2 a, f2 b) { return a + (f2){1.0f, -1.0f} * swp(b); }

// ---- xor-lane exchange: DPP (VALU-speed) for h in {1,2,8}; shfl otherwise.
template<int CTRL>
__device__ __forceinline__ float dpp_f(float v) {
  return __int_as_float(__builtin_amdgcn_update_dpp(
      __float_as_int(v), __float_as_int(v), CTRL, 0xF, 0xF, true));
}
template<int H>
__device__ __forceinline__ float xlane(float v) {
  if constexpr (H == 1)      return dpp_f<0xB1>(v);    // quad_perm [1,0,3,2]
  else if constexpr (H == 2) return dpp_f<0x4E>(v);    // quad_perm [2,3,0,1]
  else if constexpr (H == 8) return dpp_f<0x128>(v);   // row_ror:8 (xor8 in 16-row)
  else return __shfl_xor(v, H, 64);
}
template<int H>
__device__ __forceinline__ f2 xlane2(f2 v) {
  return (f2){xlane<H>(v.x), xlane<H>(v.y)};
}
__device__ __forceinline__ f2 shfl2(f2 v, int l) {
  return (f2){__shfl(v.x, l, 64), __shfl(v.y, l, 64)};
}
__device__ __forceinline__ float bcast0(float v) {
  return __int_as_float(__builtin_amdgcn_readfirstlane(__float_as_int(v)));
}

__device__ __forceinline__ void fft4_fwd(f2* v) {
  f2 t0 = v[0] + v[2], t1 = v[0] - v[2];
  f2 t2 = v[1] + v[3], t3 = v[1] - v[3];
  v[0] = t0 + t2; v[2] = t0 - t2;
  v[1] = subi(t1, t3);
  v[3] = addi(t1, t3);
}
__device__ __forceinline__ void fft4_inv(f2* v) {
  f2 t0 = v[0] + v[2], t1 = v[0] - v[2];
  f2 t2 = v[1] + v[3], t3 = v[1] - v[3];
  v[0] = t0 + t2; v[2] = t0 - t2;
  v[1] = addi(t1, t3);
  v[3] = subi(t1, t3);
}

// Butterfly stages with LANE-MASKED twiddles (lo lanes hold W=(1,0): no
// cndmask selects anywhere). sg = +1 lo / -1 hi.
template<int H>
__device__ __forceinline__ void fwd_stage(f2* v, float wr, f2 wn, float sg) {
#pragma unroll
  for (int b = 0; b < 4; ++b) {
    f2 p = xlane2<H>(v[b]);
    f2 t = sg * v[b] + p;          // lo: v+p ; hi: p-v
    v[b] = cmulp(t, wr, wn);       // lo: *1 ; hi: *e^{-i th}
  }
}
template<int H>
__device__ __forceinline__ void inv_stage(f2* v, float wr, f2 wn, float sg) {
#pragma unroll
  for (int b = 0; b < 4; ++b) {
    f2 u = cmulpc(v[b], wr, wn);   // lo: v ; hi: v*e^{+i th} (conj W)
    f2 p = xlane2<H>(u);
    v[b] = sg * u + p;             // lo: u+p ; hi: p-u
  }
}

// 256-point FFT: time n = 64a+lane (slot a) <-> freq k = 4*rev6(lane)+b.
__device__ __forceinline__ void fft256_fwd(f2* v,
                                           const float* twFc, const f2* twFn,
                                           const float* wrS, const f2* wnS,
                                           const float* sgS) {
  fft4_fwd(v);
#pragma unroll
  for (int b = 1; b < 4; ++b) v[b] = cmulp(v[b], twFc[b-1], twFn[b-1]);
  fwd_stage<32>(v, wrS[0], wnS[0], sgS[0]);
  fwd_stage<16>(v, wrS[1], wnS[1], sgS[1]);
  fwd_stage<8> (v, wrS[2], wnS[2], sgS[2]);
  fwd_stage<4> (v, wrS[3], wnS[3], sgS[3]);
  fwd_stage<2> (v, wrS[4], wnS[4], sgS[4]);
  fwd_stage<1> (v, wrS[5], wnS[5], sgS[5]);
}

__device__ __forceinline__ void ifft256(f2* v,
                                        const float* twFc, const f2* twFn,
                                        const float* wrS, const f2* wnS,
                                        const float* sgS) {
  inv_stage<1> (v, wrS[5], wnS[5], sgS[5]);
  inv_stage<2> (v, wrS[4], wnS[4], sgS[4]);
  inv_stage<4> (v, wrS[3], wnS[3], sgS[3]);
  inv_stage<8> (v, wrS[2], wnS[2], sgS[2]);
  inv_stage<16>(v, wrS[1], wnS[1], sgS[1]);
  inv_stage<32>(v, wrS[0], wnS[0], sgS[0]);
#pragma unroll
  for (int b = 1; b < 4; ++b) v[b] = cmulpc(v[b], twFc[b-1], twFn[b-1]);
  fft4_inv(v);
}

// Half-spectrum S[0..255] (+ real scalar S256) -> packed Z for ifft256.
__device__ __forceinline__ void half_to_z(f2* S, float S256,
                                          const float* twHc, const f2* twHn,
                                          int lane, int pl0, int plx) {
  f2 P[4];
  P[0] = shfl2(S[0], pl0);
#pragma unroll
  for (int b = 1; b < 4; ++b) P[b] = shfl2(S[4 - b], plx);
  P[0] = (lane == 0) ? (f2){S256, 0.0f} : P[0];
#pragma unroll
  for (int b = 0; b < 4; ++b) {
    f2 cP = conjf2(P[b]);
    f2 A = 0.5f * (S[b] + cP);
    f2 B = 0.5f * (S[b] - cP);
    f2 Bt = cmulp(B, twHc[b], twHn[b]);   // B * e^{+i th}
    S[b] = addi(A, Bt);
  }
}

// Per-bin mode update exploiting Hermitian symmetry (no cross-lane ops).
__device__ __forceinline__ void mode_update4(const f2* X, const f2* V, f2* U,
                                             const float* lam1, const float* lam2,
                                             float om, float f0) {
#pragma unroll
  for (int b = 0; b < 4; ++b) {
    float f = f0 + (float)b * (1.0f / 512.0f);
    float dfp = f - om;
    float dfm = f + om;
    float gp = __builtin_amdgcn_rcpf(fmaf(1600.0f * dfp, dfp, 1.0f));
    float gm = __builtin_amdgcn_rcpf(fmaf(1600.0f * dfm, dfm, 1.0f));
    float gs = 0.5f * (gp + gm);
    f2 D = X[b] - V[b];
    float lt = 0.25f * fmaf(lam1[b], gp, lam2[b] * gm);
    U[b] = gs * D + (f2){lt, 0.0f};
  }
}

// One wave per (b,d) sequence (round-13 structure, verified at 219 us).
// Omegas staged in d_ws so the single fused epilogue kernel can recompute
// per-batch flags independently (no cross-block ordering on `out`).
__global__ __attribute__((amdgpu_flat_work_group_size(256, 256),
                          amdgpu_waves_per_eu(4, 4),
                          amdgpu_num_vgpr(96)))
void vmd_kernel(const float* __restrict__ x, float* __restrict__ out,
                float* __restrict__ ws) {
  __shared__ float stage[4 * 512];    // [seq][n]; x resident during loop, reused for out
  __shared__ float ldsLam[4 * 512];   // psi-permuted lambda per wave

  const int tid = threadIdx.x;
  const int wv = tid >> 6;
  const int lane = tid & 63;
  const int w = (blockIdx.x >> 3) + ((blockIdx.x & 7) << 7);   // XCD swizzle
  const int g = 4 * w + wv;
  const int bb = w >> 5;
  const int d0 = (4 * w) & 127;
  const int base4 = bb * 16384 + (d0 >> 2);
  float* lamLds = ldsLam + wv * 512;
  f2* stg2 = (f2*)stage + wv * 256;   // packed (even,odd) pair view of this seq

  const int rev = (int)(__brev((unsigned)lane) >> 26);           // rev6(lane)
  const float f0 = (float)rev * (1.0f / 128.0f);
  const int plx = lane ^ 63;
  const int pl0 = (int)(__brev((unsigned)((64 - rev) & 63)) >> 26);

  // Stage twiddles, lane-masked: lo lanes = identity (wr=1, wn=0).
  float wrS[6], sgS[6]; f2 wnS[6];
#pragma unroll
  for (int s = 0; s < 6; ++s) {
    const int h = 32 >> s;
    const bool hi = (lane & h) != 0;
    float th = (float)(lane & (h - 1)) * (3.14159265358979323846f / (float)h);
    float sn, cs; sincosf(th, &sn, &cs);
    wrS[s] = hi ? cs : 1.0f;                        // W = e^{-i th}
    wnS[s] = hi ? (f2){sn, -sn} : (f2){0.0f, 0.0f};
    sgS[s] = hi ? -1.0f : 1.0f;
  }
  float twFc[3]; f2 twFn[3];
#pragma unroll
  for (int b = 1; b < 4; ++b) {
    float th = (float)(lane * b) * 0.02454369260617026f;   // 2pi/256, e^{-i th}
    float sn, cs; sincosf(th, &sn, &cs);
    twFc[b-1] = cs; twFn[b-1] = (f2){sn, -sn};
  }
  float twHc[4]; f2 twHn[4];
#pragma unroll
  for (int b = 0; b < 4; ++b) {
    float th = (float)(4 * rev + b) * 0.01227184630308513f; // 2pi/512, e^{+i th}
    float sn, cs; sincosf(th, &sn, &cs);
    twHc[b] = cs; twHn[b] = (f2){-sn, sn};
  }

  // ---- load x: float4 (n, d0..d0+3) -> stage[seq][n]; zero lambda ----
  {
    const float4* x4 = (const float4*)x;
    float4 va = x4[base4 + tid * 32];
    float4 vb = x4[base4 + (tid + 256) * 32];
    stage[tid]        = va.x; stage[512 + tid]        = va.y;
    stage[1024 + tid] = va.z; stage[1536 + tid]       = va.w;
    stage[tid + 256]        = vb.x; stage[512 + tid + 256]  = vb.y;
    stage[1024 + tid + 256] = vb.z; stage[1536 + tid + 256] = vb.w;
#pragma unroll
    for (int j = 0; j < 8; ++j) ldsLam[tid * 8 + j] = 0.0f;
  }
  __syncthreads();

  // ---- initial FFT input straight from LDS (x stays resident in stage) ----
  f2 z[4];
#pragma unroll
  for (int a = 0; a < 4; ++a) z[a] = stg2[64 * a + lane];
  fft256_fwd(z, twFc, twFn, wrS, wnS, sgS);
  f2 X[4];
  float X256;
  {
    f2 P[4];
    P[0] = shfl2(z[0], pl0);
#pragma unroll
    for (int b = 1; b < 4; ++b) P[b] = shfl2(z[4 - b], plx);
    X256 = bcast0(z[0].x - z[0].y);
#pragma unroll
    for (int b = 0; b < 4; ++b) {
      f2 cP = conjf2(P[b]);
      f2 E = 0.5f * (z[b] + cP);
      f2 O = 0.5f * (f2){1.0f, -1.0f} * swp(z[b] - cP);   // -i*(z-cP)/2
      X[b] = E + cmulpc(O, twHc[b], twHn[b]);             // O * e^{-i th}
    }
  }

  f2 U0[4], U1[4], lam[4];
#pragma unroll
  for (int b = 0; b < 4; ++b) {
    U0[b] = (f2){0.0f, 0.0f}; U1[b] = (f2){0.0f, 0.0f};
    lam[b] = (f2){0.0f, 0.0f};
  }
  float U0_256 = 0.0f, U1_256 = 0.0f;
  float om0 = 0.0f, om1 = 0.0f;

  const int psiE = 256 * (lane & 1) + (lane >> 1);   // lambda write base

#pragma unroll 1
  for (int it = 0; it < 50; ++it) {
    float lam1[4], lam2[4];
#pragma unroll
    for (int b = 0; b < 4; ++b) lam1[b] = lamLds[128 * b + 64 + rev];
    lam2[0] = lamLds[64 - rev];
#pragma unroll
    for (int b = 1; b < 4; ++b) lam2[b] = lamLds[128 * (4 - b) + 63 - rev];
    float lam0 = lamLds[0];

    mode_update4(X, U1, U0, lam1, lam2, om0, f0);
    {
      float dm = 0.5f + om0;
      float gg = __builtin_amdgcn_rcpf(fmaf(1600.0f * dm, dm, 1.0f));
      U0_256 = (X256 - U1_256 + 0.5f * lam0) * gg;
    }
    mode_update4(X, U0, U1, lam1, lam2, om1, f0);
    {
      float dm = 0.5f + om1;
      float gg = __builtin_amdgcn_rcpf(fmaf(1600.0f * dm, dm, 1.0f));
      U1_256 = (X256 - U0_256 + 0.5f * lam0) * gg;
    }

    // omega: packed (num,den) pairs; DPP for the 8/2/1 reduce steps
    f2 s0 = (f2){0.0f, 0.0f}, s1 = (f2){0.0f, 0.0f};
#pragma unroll
    for (int b = 0; b < 4; ++b) {
      float f = f0 + (float)b * (1.0f / 512.0f);
      float p0 = fmaf(U0[b].x, U0[b].x, U0[b].y * U0[b].y);
      float p1 = fmaf(U1[b].x, U1[b].x, U1[b].y * U1[b].y);
      s0 = s0 + (f2){f * p0, p0};
      s1 = s1 + (f2){f * p1, p1};
    }
    s0 = s0 + xlane2<32>(s0);  s1 = s1 + xlane2<32>(s1);
    s0 = s0 + xlane2<16>(s0);  s1 = s1 + xlane2<16>(s1);
    s0 = s0 + xlane2<8>(s0);   s1 = s1 + xlane2<8>(s1);
    s0 = s0 + xlane2<4>(s0);   s1 = s1 + xlane2<4>(s1);
    s0 = s0 + xlane2<2>(s0);   s1 = s1 + xlane2<2>(s1);
    s0 = s0 + xlane2<1>(s0);   s1 = s1 + xlane2<1>(s1);
    om0 = s0.x / (s0.y + 1e-7f);
    om1 = s1.x / (s1.y + 1e-7f);

    if (it < 49) {   // last iteration's lambda is never consumed
#pragma unroll
      for (int b = 0; b < 4; ++b) z[b] = U0[b] + U1[b];
      float S256 = U0_256 + U1_256;
      half_to_z(z, S256, twHc, twHn, lane, pl0, plx);
      ifft256(z, twFc, twFn, wrS, wnS, sgS);
#pragma unroll
      for (int a = 0; a < 4; ++a) {
        f2 xa = stg2[64 * a + lane];               // x from LDS
        lam[a] = lam[a] + 0.001f * (xa - z[a] * (1.0f / 256.0f));
        lamLds[psiE + 32 * a]       = lam[a].x;
        lamLds[psiE + 32 * a + 128] = lam[a].y;
      }
      asm volatile("s_waitcnt lgkmcnt(0)" ::: "memory");
    }
  }

  // ---- final modes: half->z, ifft256, pack to stage, float4 stores ----
  float4* o4 = (float4*)out;
#pragma unroll
  for (int b = 0; b < 4; ++b) z[b] = U0[b];
  half_to_z(z, U0_256, twHc, twHn, lane, pl0, plx);
  ifft256(z, twFc, twFn, wrS, wnS, sgS);
  __syncthreads();   // all waves done reading x from stage
#pragma unroll
  for (int a = 0; a < 4; ++a) stg2[64 * a + lane] = z[a] * (1.0f / 256.0f);
  __syncthreads();
#pragma unroll
  for (int r = 0; r < 2; ++r) {
    const int n = tid + r * 256;
    float4 v;
    v.x = stage[n]; v.y = stage[512 + n]; v.z = stage[1024 + n]; v.w = stage[1536 + n];
    o4[FIELD / 4 + base4 + n * 32] = v;
  }
  __syncthreads();
#pragma unroll
  for (int b = 0; b < 4; ++b) z[b] = U1[b];
  half_to_z(z, U1_256, twHc, twHn, lane, pl0, plx);
  ifft256(z, twFc, twFn, wrS, wnS, sgS);
#pragma unroll
  for (int a = 0; a < 4; ++a) stg2[64 * a + lane] = z[a] * (1.0f / 256.0f);
  __syncthreads();
#pragma unroll
  for (int r = 0; r < 2; ++r) {
    const int n = tid + r * 256;
    float4 v;
    v.x = stage[n]; v.y = stage[512 + n]; v.z = stage[1024 + n]; v.w = stage[1536 + n];
    o4[2 * FIELD / 4 + base4 + n * 32] = v;
  }

  if (lane == 0) {
    ws[g] = om0;             // omega staging in workspace (read-only for epi)
    ws[NSEQ + g] = om1;
  }
}

// Fused epilogue: per-batch flag recomputed per block (64 ws reads + wave
// reduce), trend slice zeroed, period/res conditionally swapped. One dispatch
// replaces order + swap + memset.
__global__ __launch_bounds__(256) void epi_kernel(float* __restrict__ out,
                                                  const float* __restrict__ ws) {
  const int tid = threadIdx.x;
  const int blk = blockIdx.x;          // 0..2047; 64 blocks per batch
  const int bb = blk >> 6;
  __shared__ float flagS;
  if (tid < 64) {
    float o0 = ws[bb * 128 + tid] + ws[bb * 128 + 64 + tid];
    float o1 = ws[NSEQ + bb * 128 + tid] + ws[NSEQ + bb * 128 + 64 + tid];
#pragma unroll
    for (int off = 32; off >= 1; off >>= 1) {
      o0 += __shfl_xor(o0, off, 64);
      o1 += __shfl_xor(o1, off, 64);
    }
    if (tid == 0) flagS = (o0 > o1) ? 1.0f : 0.0f;   // swap iff mean0 > mean1
  }
  __syncthreads();
  const bool sw = flagS > 0.5f;
  float4* o4 = (float4*)out;
  const int i = blk * 256 + tid;       // float4 index within trend field
  o4[i] = (float4){0.0f, 0.0f, 0.0f, 0.0f};
  if (sw) {
    float4 p = o4[FIELD / 4 + i];
    float4 r = o4[2 * FIELD / 4 + i];
    o4[FIELD / 4 + i] = r;
    o4[2 * FIELD / 4 + i] = p;
  }
}

extern "C" void kernel_launch(void* const* d_in, const int* in_sizes, int n_in,
                              void* d_out, int out_size, void* d_ws, size_t ws_size,
                              hipStream_t stream) {
  (void)in_sizes; (void)n_in; (void)ws_size; (void)out_size;
  const float* x = (const float*)d_in[0];
  float* out = (float*)d_out;
  float* ws = (float*)d_ws;
  vmd_kernel<<<NSEQ / 4, 256, 0, stream>>>(x, out, ws);
  epi_kernel<<<FIELD / 1024, 256, 0, stream>>>(out, ws);
}

// Round 16
// 239.102 us; speedup vs baseline: 1.4207x; 1.0521x over previous
//
#include <hip/hip_runtime.h>
#include <math.h>

#define FIELD 2097152   // 32*512*128
#define NSEQ  4096      // 32*128 sequences

typedef float f2 __attribute__((ext_vector_type(2)));   // (re, im) -> VGPR pair

__device__ __forceinline__ f2 swp(f2 a) { return __builtin_shufflevector(a, a, 1, 0); }
__device__ __forceinline__ f2 conjf2(f2 a) { return (f2){a.x, -a.y}; }
// multiply by (c + i s), with ns = (-s, s): 1 pk_mul + 1 pk_fma (swap -> op_sel)
__device__ __forceinline__ f2 cmulp(f2 a, float c, f2 ns)  { return c * a + ns * swp(a); }
// multiply by (c - i s)
__device__ __forceinline__ f2 cmulpc(f2 a, float c, f2 ns) { return c * a - ns * swp(a); }
// a + i*b  /  a - i*b
__device__ __forceinline__ f2 addi(f2 a, f2 b) { return a + (f2){-1.0f, 1.0f} * swp(b); }
__device__ __forceinline__ f2 subi(f2 a, f2 b) { return a + (f2){1.0f, -1.0f} * swp(b); }

// ---- xor-lane exchange: DPP (VALU-speed) for h in {1,2,4,8}; bpermute-based
// ---- __shfl_xor only for cross-row h in {16,32}. All 64 lanes active.
template<int CTRL>
__device__ __forceinline__ float dpp_f(float v) {
  return __int_as_float(__builtin_amdgcn_update_dpp(
      __float_as_int(v), __float_as_int(v), CTRL, 0xF, 0xF, true));
}
template<int CTRL>
__device__ __forceinline__ float dpp0_f(float v) {   // old=0, invalid lanes -> 0
  return __int_as_float(__builtin_amdgcn_update_dpp(
      0, __float_as_int(v), CTRL, 0xF, 0xF, true));
}
template<int H>
__device__ __forceinline__ float xlane(float v) {
  if constexpr (H == 1)      return dpp_f<0xB1>(v);    // quad_perm [1,0,3,2] = xor1
  else if constexpr (H == 2) return dpp_f<0x4E>(v);    // quad_perm [2,3,0,1] = xor2
  else if constexpr (H == 4) return dpp_f<0x141>(dpp_f<0x1B>(v)); // xor7 o xor3 = xor4
  else if constexpr (H == 8) return dpp_f<0x128>(v);   // row_ror:8 = xor8
  else return __shfl_xor(v, H, 64);
}
template<int H>
__device__ __forceinline__ f2 xlane2(f2 v) {
  return (f2){xlane<H>(v.x), xlane<H>(v.y)};
}
__device__ __forceinline__ f2 shfl2(f2 v, int l) {
  return (f2){__shfl(v.x, l, 64), __shfl(v.y, l, 64)};
}
__device__ __forceinline__ float bcast0(float v) {
  return __int_as_float(__builtin_amdgcn_readfirstlane(__float_as_int(v)));
}
// 64-lane sum, zero DS ops: row_shr prefix adds + row_bcast15/31, total in
// lane 63, broadcast via readlane (SGPR).
__device__ __forceinline__ float wave_sum(float v) {
  v += dpp0_f<0x111>(v);   // row_shr:1
  v += dpp0_f<0x112>(v);   // row_shr:2
  v += dpp0_f<0x114>(v);   // row_shr:4
  v += dpp0_f<0x118>(v);   // row_shr:8  -> lane 15/31/47/63 hold row sums
  v += dpp0_f<0x142>(v);   // row_bcast15 -> lanes 31,63 hold half sums
  v += dpp0_f<0x143>(v);   // row_bcast31 -> lane 63 holds total
  return __int_as_float(__builtin_amdgcn_readlane(__float_as_int(v), 63));
}

__device__ __forceinline__ void fft4_fwd(f2* v) {
  f2 t0 = v[0] + v[2], t1 = v[0] - v[2];
  f2 t2 = v[1] + v[3], t3 = v[1] - v[3];
  v[0] = t0 + t2; v[2] = t0 - t2;
  v[1] = subi(t1, t3);
  v[3] = addi(t1, t3);
}
__device__ __forceinline__ void fft4_inv(f2* v) {
  f2 t0 = v[0] + v[2], t1 = v[0] - v[2];
  f2 t2 = v[1] + v[3], t3 = v[1] - v[3];
  v[0] = t0 + t2; v[2] = t0 - t2;
  v[1] = addi(t1, t3);
  v[3] = subi(t1, t3);
}

// Butterfly stages with LANE-MASKED twiddles (lo lanes hold W=(1,0): no
// cndmask selects anywhere). sg = +1 lo / -1 hi.
template<int H>
__device__ __forceinline__ void fwd_stage(f2* v, float wr, f2 wn, float sg) {
#pragma unroll
  for (int b = 0; b < 4; ++b) {
    f2 p = xlane2<H>(v[b]);
    f2 t = sg * v[b] + p;          // lo: v+p ; hi: p-v
    v[b] = cmulp(t, wr, wn);       // lo: *1 ; hi: *e^{-i th}
  }
}
template<int H>
__device__ __forceinline__ void inv_stage(f2* v, float wr, f2 wn, float sg) {
#pragma unroll
  for (int b = 0; b < 4; ++b) {
    f2 u = cmulpc(v[b], wr, wn);   // lo: v ; hi: v*e^{+i th} (conj W)
    f2 p = xlane2<H>(u);
    v[b] = sg * u + p;             // lo: u+p ; hi: p-u
  }
}

// 256-point FFT: time n = 64a+lane (slot a) <-> freq k = 4*rev6(lane)+b.
__device__ __forceinline__ void fft256_fwd(f2* v,
                                           const float* twFc, const f2* twFn,
                                           const float* wrS, const f2* wnS,
                                           const float* sgS) {
  fft4_fwd(v);
#pragma unroll
  for (int b = 1; b < 4; ++b) v[b] = cmulp(v[b], twFc[b-1], twFn[b-1]);
  fwd_stage<32>(v, wrS[0], wnS[0], sgS[0]);
  fwd_stage<16>(v, wrS[1], wnS[1], sgS[1]);
  fwd_stage<8> (v, wrS[2], wnS[2], sgS[2]);
  fwd_stage<4> (v, wrS[3], wnS[3], sgS[3]);
  fwd_stage<2> (v, wrS[4], wnS[4], sgS[4]);
  fwd_stage<1> (v, wrS[5], wnS[5], sgS[5]);
}

__device__ __forceinline__ void ifft256(f2* v,
                                        const float* twFc, const f2* twFn,
                                        const float* wrS, const f2* wnS,
                                        const float* sgS) {
  inv_stage<1> (v, wrS[5], wnS[5], sgS[5]);
  inv_stage<2> (v, wrS[4], wnS[4], sgS[4]);
  inv_stage<4> (v, wrS[3], wnS[3], sgS[3]);
  inv_stage<8> (v, wrS[2], wnS[2], sgS[2]);
  inv_stage<16>(v, wrS[1], wnS[1], sgS[1]);
  inv_stage<32>(v, wrS[0], wnS[0], sgS[0]);
#pragma unroll
  for (int b = 1; b < 4; ++b) v[b] = cmulpc(v[b], twFc[b-1], twFn[b-1]);
  fft4_inv(v);
}

// Half-spectrum S[0..255] (+ real scalar S256) -> packed Z for ifft256.
__device__ __forceinline__ void half_to_z(f2* S, float S256,
                                          const float* twHc, const f2* twHn,
                                          int lane, int pl0, int plx) {
  f2 P[4];
  P[0] = shfl2(S[0], pl0);
#pragma unroll
  for (int b = 1; b < 4; ++b) P[b] = shfl2(S[4 - b], plx);
  P[0] = (lane == 0) ? (f2){S256, 0.0f} : P[0];
#pragma unroll
  for (int b = 0; b < 4; ++b) {
    f2 cP = conjf2(P[b]);
    f2 A = 0.5f * (S[b] + cP);
    f2 B = 0.5f * (S[b] - cP);
    f2 Bt = cmulp(B, twHc[b], twHn[b]);   // B * e^{+i th}
    S[b] = addi(A, Bt);
  }
}

// Per-bin mode update exploiting Hermitian symmetry (no cross-lane ops).
__device__ __forceinline__ void mode_update4(const f2* X, const f2* V, f2* U,
                                             const float* lam1, const float* lam2,
                                             float om, float f0) {
#pragma unroll
  for (int b = 0; b < 4; ++b) {
    float f = f0 + (float)b * (1.0f / 512.0f);
    float dfp = f - om;
    float dfm = f + om;
    float gp = __builtin_amdgcn_rcpf(fmaf(1600.0f * dfp, dfp, 1.0f));
    float gm = __builtin_amdgcn_rcpf(fmaf(1600.0f * dfm, dfm, 1.0f));
    float gs = 0.5f * (gp + gm);
    f2 D = X[b] - V[b];
    float lt = 0.25f * fmaf(lam1[b], gp, lam2[b] * gm);
    U[b] = gs * D + (f2){lt, 0.0f};
  }
}

// One wave per (b,d) sequence. DS-pipe relief round: omega reduce is pure
// DPP (zero DS ops), xor4 is 2xDPP, omega divide is rcp. Only h=16/32
// exchanges, the Hermitian pack, and lambda LDS remain on the DS pipe.
__global__ __attribute__((amdgpu_flat_work_group_size(256, 256),
                          amdgpu_waves_per_eu(4, 4),
                          amdgpu_num_vgpr(96)))
void vmd_kernel(const float* __restrict__ x, float* __restrict__ out,
                float* __restrict__ ws) {
  __shared__ float stage[4 * 512];    // [seq][n]; x resident during loop, reused for out
  __shared__ float ldsLam[4 * 512];   // psi-permuted lambda per wave

  const int tid = threadIdx.x;
  const int wv = tid >> 6;
  const int lane = tid & 63;
  const int w = (blockIdx.x >> 3) + ((blockIdx.x & 7) << 7);   // XCD swizzle
  const int g = 4 * w + wv;
  const int bb = w >> 5;
  const int d0 = (4 * w) & 127;
  const int base4 = bb * 16384 + (d0 >> 2);
  float* lamLds = ldsLam + wv * 512;
  f2* stg2 = (f2*)stage + wv * 256;   // packed (even,odd) pair view of this seq

  const int rev = (int)(__brev((unsigned)lane) >> 26);           // rev6(lane)
  const float f0 = (float)rev * (1.0f / 128.0f);
  const int plx = lane ^ 63;
  const int pl0 = (int)(__brev((unsigned)((64 - rev) & 63)) >> 26);

  // Stage twiddles, lane-masked: lo lanes = identity (wr=1, wn=0).
  float wrS[6], sgS[6]; f2 wnS[6];
#pragma unroll
  for (int s = 0; s < 6; ++s) {
    const int h = 32 >> s;
    const bool hi = (lane & h) != 0;
    float th = (float)(lane & (h - 1)) * (3.14159265358979323846f / (float)h);
    float sn, cs; sincosf(th, &sn, &cs);
    wrS[s] = hi ? cs : 1.0f;                        // W = e^{-i th}
    wnS[s] = hi ? (f2){sn, -sn} : (f2){0.0f, 0.0f};
    sgS[s] = hi ? -1.0f : 1.0f;
  }
  float twFc[3]; f2 twFn[3];
#pragma unroll
  for (int b = 1; b < 4; ++b) {
    float th = (float)(lane * b) * 0.02454369260617026f;   // 2pi/256, e^{-i th}
    float sn, cs; sincosf(th, &sn, &cs);
    twFc[b-1] = cs; twFn[b-1] = (f2){sn, -sn};
  }
  float twHc[4]; f2 twHn[4];
#pragma unroll
  for (int b = 0; b < 4; ++b) {
    float th = (float)(4 * rev + b) * 0.01227184630308513f; // 2pi/512, e^{+i th}
    float sn, cs; sincosf(th, &sn, &cs);
    twHc[b] = cs; twHn[b] = (f2){-sn, sn};
  }

  // ---- load x: float4 (n, d0..d0+3) -> stage[seq][n]; zero lambda ----
  {
    const float4* x4 = (const float4*)x;
    float4 va = x4[base4 + tid * 32];
    float4 vb = x4[base4 + (tid + 256) * 32];
    stage[tid]        = va.x; stage[512 + tid]        = va.y;
    stage[1024 + tid] = va.z; stage[1536 + tid]       = va.w;
    stage[tid + 256]        = vb.x; stage[512 + tid + 256]  = vb.y;
    stage[1024 + tid + 256] = vb.z; stage[1536 + tid + 256] = vb.w;
#pragma unroll
    for (int j = 0; j < 8; ++j) ldsLam[tid * 8 + j] = 0.0f;
  }
  __syncthreads();

  // ---- initial FFT input straight from LDS (x stays resident in stage) ----
  f2 z[4];
#pragma unroll
  for (int a = 0; a < 4; ++a) z[a] = stg2[64 * a + lane];
  fft256_fwd(z, twFc, twFn, wrS, wnS, sgS);
  f2 X[4];
  float X256;
  {
    f2 P[4];
    P[0] = shfl2(z[0], pl0);
#pragma unroll
    for (int b = 1; b < 4; ++b) P[b] = shfl2(z[4 - b], plx);
    X256 = bcast0(z[0].x - z[0].y);
#pragma unroll
    for (int b = 0; b < 4; ++b) {
      f2 cP = conjf2(P[b]);
      f2 E = 0.5f * (z[b] + cP);
      f2 O = 0.5f * (f2){1.0f, -1.0f} * swp(z[b] - cP);   // -i*(z-cP)/2
      X[b] = E + cmulpc(O, twHc[b], twHn[b]);             // O * e^{-i th}
    }
  }

  f2 U0[4], U1[4], lam[4];
#pragma unroll
  for (int b = 0; b < 4; ++b) {
    U0[b] = (f2){0.0f, 0.0f}; U1[b] = (f2){0.0f, 0.0f};
    lam[b] = (f2){0.0f, 0.0f};
  }
  float U0_256 = 0.0f, U1_256 = 0.0f;
  float om0 = 0.0f, om1 = 0.0f;

  const int psiE = 256 * (lane & 1) + (lane >> 1);   // lambda write base

#pragma unroll 1
  for (int it = 0; it < 50; ++it) {
    float lam1[4], lam2[4];
#pragma unroll
    for (int b = 0; b < 4; ++b) lam1[b] = lamLds[128 * b + 64 + rev];
    lam2[0] = lamLds[64 - rev];
#pragma unroll
    for (int b = 1; b < 4; ++b) lam2[b] = lamLds[128 * (4 - b) + 63 - rev];
    float lam0 = lamLds[0];

    mode_update4(X, U1, U0, lam1, lam2, om0, f0);
    {
      float dm = 0.5f + om0;
      float gg = __builtin_amdgcn_rcpf(fmaf(1600.0f * dm, dm, 1.0f));
      U0_256 = (X256 - U1_256 + 0.5f * lam0) * gg;
    }
    mode_update4(X, U0, U1, lam1, lam2, om1, f0);
    {
      float dm = 0.5f + om1;
      float gg = __builtin_amdgcn_rcpf(fmaf(1600.0f * dm, dm, 1.0f));
      U1_256 = (X256 - U0_256 + 0.5f * lam0) * gg;
    }

    // omega: per-bin accumulate, then pure-DPP wave sums (zero DS ops)
    f2 s0 = (f2){0.0f, 0.0f}, s1 = (f2){0.0f, 0.0f};
#pragma unroll
    for (int b = 0; b < 4; ++b) {
      float f = f0 + (float)b * (1.0f / 512.0f);
      float p0 = fmaf(U0[b].x, U0[b].x, U0[b].y * U0[b].y);
      float p1 = fmaf(U1[b].x, U1[b].x, U1[b].y * U1[b].y);
      s0 = s0 + (f2){f * p0, p0};
      s1 = s1 + (f2){f * p1, p1};
    }
    float n0 = wave_sum(s0.x), d0s = wave_sum(s0.y);
    float n1 = wave_sum(s1.x), d1s = wave_sum(s1.y);
    om0 = n0 * __builtin_amdgcn_rcpf(d0s + 1e-7f);
    om1 = n1 * __builtin_amdgcn_rcpf(d1s + 1e-7f);

    if (it < 49) {   // last iteration's lambda is never consumed
#pragma unroll
      for (int b = 0; b < 4; ++b) z[b] = U0[b] + U1[b];
      float S256 = U0_256 + U1_256;
      half_to_z(z, S256, twHc, twHn, lane, pl0, plx);
      ifft256(z, twFc, twFn, wrS, wnS, sgS);
#pragma unroll
      for (int a = 0; a < 4; ++a) {
        f2 xa = stg2[64 * a + lane];               // x from LDS
        lam[a] = lam[a] + 0.001f * (xa - z[a] * (1.0f / 256.0f));
        lamLds[psiE + 32 * a]       = lam[a].x;
        lamLds[psiE + 32 * a + 128] = lam[a].y;
      }
      asm volatile("s_waitcnt lgkmcnt(0)" ::: "memory");
    }
  }

  // ---- final modes: half->z, ifft256, pack to stage, float4 stores ----
  float4* o4 = (float4*)out;
#pragma unroll
  for (int b = 0; b < 4; ++b) z[b] = U0[b];
  half_to_z(z, U0_256, twHc, twHn, lane, pl0, plx);
  ifft256(z, twFc, twFn, wrS, wnS, sgS);
  __syncthreads();   // all waves done reading x from stage
#pragma unroll
  for (int a = 0; a < 4; ++a) stg2[64 * a + lane] = z[a] * (1.0f / 256.0f);
  __syncthreads();
#pragma unroll
  for (int r = 0; r < 2; ++r) {
    const int n = tid + r * 256;
    float4 v;
    v.x = stage[n]; v.y = stage[512 + n]; v.z = stage[1024 + n]; v.w = stage[1536 + n];
    o4[FIELD / 4 + base4 + n * 32] = v;
  }
  __syncthreads();
#pragma unroll
  for (int b = 0; b < 4; ++b) z[b] = U1[b];
  half_to_z(z, U1_256, twHc, twHn, lane, pl0, plx);
  ifft256(z, twFc, twFn, wrS, wnS, sgS);
#pragma unroll
  for (int a = 0; a < 4; ++a) stg2[64 * a + lane] = z[a] * (1.0f / 256.0f);
  __syncthreads();
#pragma unroll
  for (int r = 0; r < 2; ++r) {
    const int n = tid + r * 256;
    float4 v;
    v.x = stage[n]; v.y = stage[512 + n]; v.z = stage[1024 + n]; v.w = stage[1536 + n];
    o4[2 * FIELD / 4 + base4 + n * 32] = v;
  }

  if (lane == 0) {
    ws[g] = om0;             // omega staging in workspace (read-only for epi)
    ws[NSEQ + g] = om1;
  }
}

// Fused epilogue: per-batch flag recomputed per block (64 ws reads + wave
// reduce), trend slice zeroed, period/res conditionally swapped.
__global__ __launch_bounds__(256) void epi_kernel(float* __restrict__ out,
                                                  const float* __restrict__ ws) {
  const int tid = threadIdx.x;
  const int blk = blockIdx.x;          // 0..2047; 64 blocks per batch
  const int bb = blk >> 6;
  __shared__ float flagS;
  if (tid < 64) {
    float o0 = ws[bb * 128 + tid] + ws[bb * 128 + 64 + tid];
    float o1 = ws[NSEQ + bb * 128 + tid] + ws[NSEQ + bb * 128 + 64 + tid];
#pragma unroll
    for (int off = 32; off >= 1; off >>= 1) {
      o0 += __shfl_xor(o0, off, 64);
      o1 += __shfl_xor(o1, off, 64);
    }
    if (tid == 0) flagS = (o0 > o1) ? 1.0f : 0.0f;   // swap iff mean0 > mean1
  }
  __syncthreads();
  const bool sw = flagS > 0.5f;
  float4* o4 = (float4*)out;
  const int i = blk * 256 + tid;       // float4 index within trend field
  o4[i] = (float4){0.0f, 0.0f, 0.0f, 0.0f};
  if (sw) {
    float4 p = o4[FIELD / 4 + i];
    float4 r = o4[2 * FIELD / 4 + i];
    o4[FIELD / 4 + i] = r;
    o4[2 * FIELD / 4 + i] = p;
  }
}

extern "C" void kernel_launch(void* const* d_in, const int* in_sizes, int n_in,
                              void* d_out, int out_size, void* d_ws, size_t ws_size,
                              hipStream_t stream) {
  (void)in_sizes; (void)n_in; (void)ws_size; (void)out_size;
  const float* x = (const float*)d_in[0];
  float* out = (float*)d_out;
  float* ws = (float*)d_ws;
  vmd_kernel<<<NSEQ / 4, 256, 0, stream>>>(x, out, ws);
  epi_kernel<<<FIELD / 1024, 256, 0, stream>>>(out, ws);
}